// Round 1
// baseline (347.008 us; speedup 1.0000x reference)
//
#include <hip/hip_runtime.h>

// out[b,c,h,w] = x[b,c,h,w] * (1 - mask[b,0,h,w])   (MASK_VALUE == 0)
// B=64, C=3, H=W=512, fp32. Pure memory-bound elementwise blend.
//
// R5: 4-chunk-per-thread restructure to kill the serialized
// mask->branch->x dependency chain of R4:
//   phase A: 4 independent mask vec4 loads issued back-to-back
//   phase B: wave-uniform skip decision (__all) per chunk -- per-lane
//            skip is unneeded for correctness (x*(1-m) is 0 where m=1);
//            uniform branches keep exec full so loads cluster
//   phase C: all x loads for non-skipped chunks issued BEFORE any store
//   phase D: blend + nontemporal stores
// => 2 HBM round trips per 4 chunks instead of 2 per chunk; ~13
// outstanding loads/wave. Traffic unchanged: ~67MB mask + ~0.65*201MB x
// + 201MB out ~ 400 MB.

#define HW   (512 * 512)        // elements per plane
#define C_   3
#define B_   64
#define VPP  (HW / 4)           // 65536 vec4s per plane
#define CH   4                  // chunks per thread
#define S    (VPP / CH)         // 16384 vec4 stride between chunks

typedef float fvec4 __attribute__((ext_vector_type(4)));

__global__ __launch_bounds__(256) void random_mask_blend(
    const fvec4* __restrict__ x,     // B*C*VPP vec4s
    const fvec4* __restrict__ mask,  // B*1*VPP vec4s
    fvec4* __restrict__ out)
{
    const int t = blockIdx.x * 256 + threadIdx.x;       // [0, S)
    const int b = blockIdx.y;
    const long long mbase = (long long)b * VPP + t;
    const long long xbase = ((long long)b * C_) * VPP + t;

    // ---- phase A: all mask loads up front (independent) ----
    fvec4 m[CH];
#pragma unroll
    for (int k = 0; k < CH; ++k)
        m[k] = __builtin_nontemporal_load(&mask[mbase + k * S]);

    // ---- phase B: wave-uniform skip flags ----
    bool skip[CH];
#pragma unroll
    for (int k = 0; k < CH; ++k) {
        const bool full = (m[k].x + m[k].y + m[k].z + m[k].w == 4.0f);
        skip[k] = __all(full);          // uniform across the wave
    }

    // ---- phase C: issue ALL x loads before any store ----
    fvec4 xv[CH][C_];
#pragma unroll
    for (int k = 0; k < CH; ++k) {
        if (!skip[k]) {
#pragma unroll
            for (int c = 0; c < C_; ++c)
                xv[k][c] = __builtin_nontemporal_load(
                    &x[xbase + k * S + (long long)c * VPP]);
        }
    }

    // ---- phase D: blend + store ----
    const fvec4 z = {0.0f, 0.0f, 0.0f, 0.0f};
#pragma unroll
    for (int k = 0; k < CH; ++k) {
        const long long o = xbase + k * S;
        if (skip[k]) {
#pragma unroll
            for (int c = 0; c < C_; ++c)
                __builtin_nontemporal_store(z, &out[o + (long long)c * VPP]);
        } else {
            const fvec4 w = 1.0f - m[k];
#pragma unroll
            for (int c = 0; c < C_; ++c)
                __builtin_nontemporal_store(xv[k][c] * w,
                                            &out[o + (long long)c * VPP]);
        }
    }
}

extern "C" void kernel_launch(void* const* d_in, const int* in_sizes, int n_in,
                              void* d_out, int out_size, void* d_ws, size_t ws_size,
                              hipStream_t stream) {
    const fvec4* x    = (const fvec4*)d_in[0];
    const fvec4* mask = (const fvec4*)d_in[1];
    fvec4* out        = (fvec4*)d_out;

    dim3 grid(S / 256, B_);     // (64, 64) blocks of 256
    dim3 block(256);
    random_mask_blend<<<grid, block, 0, stream>>>(x, mask, out);
}

// Round 2
// 339.471 us; speedup vs baseline: 1.0222x; 1.0222x over previous
//
#include <hip/hip_runtime.h>

// out[b,c,h,w] = x[b,c,h,w] * (1 - mask[b,0,h,w])   (MASK_VALUE == 0)
// B=64, C=3, H=W=512, fp32. Pure memory-bound elementwise blend.
//
// R6 = R4 structure (1 pixel-vec4 per thread, all 3 channels; per-lane
// mask-skip of x loads) with ONE change: stores are CACHEABLE (no
// nontemporal hint). Rationale: out = 201 MB < 256 MB Infinity Cache
// (memory-side writeback). Cacheable stores let the kernel retire once
// dirty lines land in MALL; writeback is deferred outside the kernel's
// critical path. Loads stay nontemporal (x, mask are single-touch and
// flushed by the 805 MB poison fill each iteration) so the read streams
// don't evict our dirty output lines from MALL.
//
// A/B vs R4 (NT stores): single variable. If neutral/worse -> MALL
// absorption is zero-sum in the timed window; NT stores were right.

#define HW   (512 * 512)        // elements per plane
#define C_   3
#define B_   64
#define VPP  (HW / 4)           // 65536 vec4s per plane

typedef float fvec4 __attribute__((ext_vector_type(4)));

__global__ __launch_bounds__(256) void random_mask_blend(
    const fvec4* __restrict__ x,     // B*C*VPP vec4s
    const fvec4* __restrict__ mask,  // B*1*VPP vec4s
    fvec4* __restrict__ out)
{
    const int v = blockIdx.x * blockDim.x + threadIdx.x;  // [0, VPP)
    const int b = blockIdx.y;

    const fvec4 mv = __builtin_nontemporal_load(&mask[(long long)b * VPP + v]);
    const long long base = ((long long)b * C_) * VPP + v;

    // Fully-masked thread: out = 0 for all 3 channels, skip the x loads.
    if (mv.x + mv.y + mv.z + mv.w == 4.0f) {
        const fvec4 z = {0.0f, 0.0f, 0.0f, 0.0f};
#pragma unroll
        for (int c = 0; c < C_; ++c)
            out[base + (long long)c * VPP] = z;          // cacheable store
    } else {
        const fvec4 w = 1.0f - mv;
#pragma unroll
        for (int c = 0; c < C_; ++c) {
            const long long idx = base + (long long)c * VPP;
            const fvec4 xv = __builtin_nontemporal_load(&x[idx]);
            out[idx] = xv * w;                            // cacheable store
        }
    }
}

extern "C" void kernel_launch(void* const* d_in, const int* in_sizes, int n_in,
                              void* d_out, int out_size, void* d_ws, size_t ws_size,
                              hipStream_t stream) {
    const fvec4* x    = (const fvec4*)d_in[0];
    const fvec4* mask = (const fvec4*)d_in[1];
    fvec4* out        = (fvec4*)d_out;

    dim3 grid(VPP / 256, B_);   // (256, 64)
    dim3 block(256);
    random_mask_blend<<<grid, block, 0, stream>>>(x, mask, out);
}